// Round 12
// baseline (424.422 us; speedup 1.0000x reference)
//
#include <hip/hip_runtime.h>
#include <hip/hip_bf16.h>

#define BATCH 8
#define CIN   128
#define HH    256
#define WW    256
#define OUTC  64
#define INCH  1152   // CIN*9
#define HW    (HH*WW)

#define PXB        256                                     // bytes per xC2 pixel
#define XC2_BYTES  ((size_t)BATCH * HH * WW * PXB)         // 134217728
#define WMOD_BYTES ((size_t)BATCH * 9 * OUTC * CIN * 2)    // 1179648
#define Z_BYTES    64

typedef __attribute__((ext_vector_type(8))) short short8;
typedef __attribute__((ext_vector_type(4))) float f32x4;
typedef __attribute__((ext_vector_type(2))) float f32x2;
typedef __attribute__((ext_vector_type(4))) unsigned int u32x4;

__device__ __forceinline__ unsigned short bf16r(float f) {
    unsigned u = __builtin_bit_cast(unsigned, f);
    u += 0x7fffu + ((u >> 16) & 1u);
    return (unsigned short)(u >> 16);
}

__device__ __forceinline__ void gload16(const void* src, void* dst_lds) {
    __builtin_amdgcn_global_load_lds(
        (const __attribute__((address_space(1))) unsigned int*)src,
        (__attribute__((address_space(3))) unsigned int*)dst_lds,
        16, 0, 0);
}

// wmod[b][tap][o][c] = bf16(weight[o][c*9+tap] * style[b][c*9+tap])
__global__ void __launch_bounds__(256) wmod_kernel(const float* __restrict__ weight,
                                                   const float* __restrict__ style,
                                                   unsigned short* __restrict__ wmod) {
    int i = blockIdx.x * 256 + threadIdx.x;
    if (i >= BATCH * 9 * OUTC * CIN) return;
    int c    = i & (CIN - 1);
    int rest = i >> 7;
    int o    = rest & (OUTC - 1);
    int bt   = rest >> 6;
    int tap  = bt % 9;
    int b    = bt / 9;
    int k    = c * 9 + tap;
    wmod[i] = bf16r(weight[o * INCH + k] * style[b * INCH + k]);
}

// xC2[b][h][w][c128]: full 256B bf16 channel vector per pixel.
// Thread: c-quarter (32 ch) x 2 px; reads f32x2 lane-coalesced (512B/instr),
// writes 2 x 64B full sectors.
__global__ void __launch_bounds__(256) repack_kernel(const float* __restrict__ x,
                                                     unsigned short* __restrict__ xC) {
    const int w  = blockIdx.x * 128 + (threadIdx.x & 63) * 2;
    const int q  = threadIdx.x >> 6;       // c-quarter
    const int h  = blockIdx.y;
    const int b  = blockIdx.z;

    const float* xp = x + ((size_t)(b * CIN + q * 32)) * HW + h * WW + w;
    unsigned short* op = xC + (((size_t)(b * HH + h) * WW + w) << 7) + q * 32;

    f32x2 f[32];
#pragma unroll
    for (int j = 0; j < 32; ++j) f[j] = *(const f32x2*)(xp + (size_t)j * HW);

#pragma unroll
    for (int u = 0; u < 2; ++u) {
        unsigned pk[16];
#pragma unroll
        for (int j = 0; j < 16; ++j)
            pk[j] = (unsigned)bf16r(f[2 * j][u]) |
                    ((unsigned)bf16r(f[2 * j + 1][u]) << 16);
#pragma unroll
        for (int v = 0; v < 4; ++v) {
            u32x4 t = {pk[v * 4 + 0], pk[v * 4 + 1], pk[v * 4 + 2], pk[v * 4 + 3]};
            *(u32x4*)(op + u * 128 + v * 8) = t;
        }
    }
}

// conv8: long-pipeline march. Block 256 thr = 4 waves (wr = o-half, wc = px-half),
// tile 64o x (4h x 16w), 16 tiles marched down h. All 512 blocks resident.
// LDS xs[2][108 px][128c] (27KB x2): granule (s, gp) holds c-group
// cg = gp ^ (s&15) of halo pixel s -> B-reads even across all 8 bank groups;
// stage dest is LINEAR (gload_lds), source = permuted-contiguous xC2 pixel.
// Per tile: [stage(t+1) 7 gload16/thr] [9 taps: loadA 2-ahead (A0/A1/A2
// rotation, WAR-bounded) + 16 MFMA/tap] [16 stores] [barrier].
__global__ void __launch_bounds__(256, 2) conv8_kernel(
    const unsigned short* __restrict__ xC,
    const unsigned short* __restrict__ wmod,
    const unsigned short* __restrict__ zptr,
    float* __restrict__ out)
{
    __shared__ __align__(16) unsigned short xs_sm[2][108 * 128];

    const int tid   = threadIdx.x;         // 0..255
    const int bx    = blockIdx.x;          // 0..63: strip*16 + wt
    const int b     = blockIdx.y;
    const int strip = bx >> 4;             // 0..3 (h-strip of 64 rows)
    const int w0    = (bx & 15) * 16;

    const int wv  = tid >> 6;
    const int wr  = wv >> 1;               // o-half
    const int wc  = wv & 1;                // px-half (rows 0-1 vs 2-3)
    const int l15 = tid & 15;
    const int kg  = (tid >> 4) & 3;

    // ---- stage geometry (fixed per thread): D = tid + i*256 < 1728
    int  soff[7];                          // byte offset in b-plane at t=0, row r
    int  rr7[7];
    bool wok7[7];
    const char* xCb = (const char*)xC + ((size_t)b * HH * WW) * PXB;
#pragma unroll
    for (int i = 0; i < 7; ++i) {
        int D  = tid + i * 256;
        int Dc = (D < 1728) ? D : 0;
        int s  = Dc >> 4;
        int gp = Dc & 15;
        int cg = gp ^ (s & 15);
        int r   = s / 18;
        int col = s - r * 18;
        int wsrc = w0 - 1 + col;
        wok7[i] = (D < 1728) && ((unsigned)wsrc < WW);
        rr7[i]  = r;
        soff[i] = ((strip * 64 - 1 + r) * WW + wsrc) * PXB + cg * 16;
    }

    f32x4 acc[2][2];
    short8 A0[2][4], A1[2][4], A2[2][4];

    const unsigned short* wmb = wmod + ((size_t)(b * 9) * OUTC) * CIN;

#define LOADA(buf, tap)                                                        \
    {                                                                          \
        _Pragma("unroll") for (int mi = 0; mi < 2; ++mi)                       \
            _Pragma("unroll") for (int ck = 0; ck < 4; ++ck)                   \
                buf[mi][ck] = *(const short8*)(wmb + (size_t)(tap)*OUTC * CIN + \
                                               (wr * 32 + mi * 16 + l15) * CIN + \
                                               ck * 32 + kg * 8);              \
    }

#define COMPTAP(buf, kh, kw, xs)                                               \
    {                                                                          \
        _Pragma("unroll") for (int ck = 0; ck < 4; ++ck) {                     \
            short8 Bv[2];                                                      \
            _Pragma("unroll") for (int ni = 0; ni < 2; ++ni) {                 \
                int s = (wc * 2 + ni + (kh)) * 18 + l15 + (kw);                \
                Bv[ni] = *(const short8*)&(xs)[s * 128 +                       \
                                               (((ck * 4 + kg) ^ (s & 15)) << 3)]; \
            }                                                                  \
            _Pragma("unroll") for (int mi = 0; mi < 2; ++mi)                   \
                _Pragma("unroll") for (int ni = 0; ni < 2; ++ni)               \
                    acc[mi][ni] = __builtin_amdgcn_mfma_f32_16x16x32_bf16(     \
                        buf[mi][ck], Bv[ni], acc[mi][ni], 0, 0, 0);            \
        }                                                                      \
    }

    auto stage = [&](int t, unsigned short* dst) {
#pragma unroll
        for (int i = 0; i < 7; ++i) {
            int D = tid + i * 256;
            if (D < 1728) {
                int hh = strip * 64 + t * 4 - 1 + rr7[i];
                bool ok = wok7[i] && ((unsigned)hh < HH);
                const void* src = ok ? (const void*)(xCb + soff[i] +
                                                     (size_t)t * (4 * WW * PXB))
                                     : (const void*)zptr;
                gload16(src, (char*)dst + (size_t)D * 16);
            }
        }
    };

    // ---- prologue
    stage(0, xs_sm[0]);
    LOADA(A0, 0);
    LOADA(A1, 1);
    __syncthreads();

#pragma unroll
    for (int t = 0; t < 16; ++t) {
        const unsigned short* xs = xs_sm[t & 1];
        if (t < 15) stage(t + 1, xs_sm[(t & 1) ^ 1]);

#pragma unroll
        for (int mi = 0; mi < 2; ++mi)
#pragma unroll
            for (int ni = 0; ni < 2; ++ni) acc[mi][ni] = (f32x4){0.f, 0.f, 0.f, 0.f};

        // taps 0..8; prefetch tap+2 into rotating buffer (WAR-bounded)
        LOADA(A2, 2); COMPTAP(A0, 0, 0, xs);
        LOADA(A0, 3); COMPTAP(A1, 0, 1, xs);
        LOADA(A1, 4); COMPTAP(A2, 0, 2, xs);
        LOADA(A2, 5); COMPTAP(A0, 1, 0, xs);
        LOADA(A0, 6); COMPTAP(A1, 1, 1, xs);
        LOADA(A1, 7); COMPTAP(A2, 1, 2, xs);
        LOADA(A2, 8); COMPTAP(A0, 2, 0, xs);
        LOADA(A0, 0); COMPTAP(A1, 2, 1, xs);
        LOADA(A1, 1); COMPTAP(A2, 2, 2, xs);
        // A0 = tap0, A1 = tap1 for next tile

        // ---- store tile t
        {
            int h0t = strip * 64 + t * 4;
            float* op = out + ((size_t)b * OUTC) * HW + (size_t)h0t * WW + w0 + l15;
#pragma unroll
            for (int mi = 0; mi < 2; ++mi)
#pragma unroll
                for (int ni = 0; ni < 2; ++ni) {
                    int hrow = wc * 2 + ni;
#pragma unroll
                    for (int rr = 0; rr < 4; ++rr) {
                        int o = wr * 32 + mi * 16 + kg * 4 + rr;
                        op[(size_t)o * HW + hrow * WW] = acc[mi][ni][rr];
                    }
                }
        }
        __syncthreads();
    }
#undef LOADA
#undef COMPTAP
}

// ---------------- fallback conv (round-7 path, fp32 staging) ----------------
template <bool GW>
__global__ void __launch_bounds__(512, 4) conv_kernel(
    const float* __restrict__ x,
    const unsigned short* __restrict__ wmod,
    const float* __restrict__ weight,
    const float* __restrict__ style,
    float* __restrict__ out)
{
    __shared__ __align__(16) unsigned short xs_sm[170 * 64];

    const int tid = threadIdx.x;
    const int bx  = blockIdx.x;
    const int b   = blockIdx.y;
    const int h0  = (bx >> 3) * 8;
    const int w0  = (bx & 7) * 32;

    const int wv  = tid >> 6;
    const int wr  = wv >> 1;
    const int wc  = wv & 1;
    const int l15 = tid & 15;
    const int kg  = (tid >> 4) & 3;

    int sbase[4];
#pragma unroll
    for (int ni = 0; ni < 4; ++ni) {
        int p = wc * 64 + ni * 16 + l15;
        sbase[ni] = (p >> 5) * 34 + (p & 31);
    }

    const bool tvalid = tid < 400;
    const int scg = tvalid ? tid / 100 : 0;
    const int srw = tvalid ? tid % 100 : 0;
    const int sr  = srw / 10;
    const int swq = srw % 10;
    const int sh  = h0 - 1 + sr;
    const bool hok = (unsigned)sh < HH;
    const int wload  = w0 - 4 + swq * 4;
    const int wclamp = min(max(wload, 0), WW - 4);
    const int gbase  = (hok ? sh : 0) * WW + wclamp;

    f32x4 acc[2][4];
#pragma unroll
    for (int mi = 0; mi < 2; ++mi)
#pragma unroll
        for (int ni = 0; ni < 4; ++ni) acc[mi][ni] = (f32x4){0.f, 0.f, 0.f, 0.f};

    for (int chunk = 0; chunk < 4; ++chunk) {
        if (chunk) __syncthreads();

        if (tvalid) {
            const float* xp =
                x + ((size_t)(b * CIN + chunk * 32 + scg * 8)) * HW + gbase;
            f32x4 f[8];
#pragma unroll
            for (int j = 0; j < 8; ++j)
                f[j] = hok ? *(const f32x4*)(xp + (size_t)j * HW)
                           : (f32x4){0.f, 0.f, 0.f, 0.f};
#pragma unroll
            for (int u = 0; u < 4; ++u) {
                int w   = wload + u;
                int col = w - (w0 - 1);
                if (col >= 0 && col <= 33) {
                    bool wok = hok && ((unsigned)w < WW);
                    short8 sv;
#pragma unroll
                    for (int j = 0; j < 8; ++j)
                        sv[j] = wok ? (short)bf16r(f[j][u]) : (short)0;
                    int s = sr * 34 + col;
                    int q = s >> 1;
                    int g = (((s & 1) << 2) | scg) ^ (q & 7);
                    *(short8*)&xs_sm[q * 64 + g * 8] = sv;
                }
            }
        }
        __syncthreads();

        const unsigned short* wmb = wmod + ((size_t)(b * 9) * OUTC) * CIN + chunk * 32;
#pragma unroll
        for (int tap = 0; tap < 9; ++tap) {
            const int kh = tap / 3, kw = tap % 3;

            short8 A[2];
            if (GW) {
                const unsigned short* wt = wmb + (size_t)tap * OUTC * CIN;
#pragma unroll
                for (int mi = 0; mi < 2; ++mi)
                    A[mi] = *(const short8*)(wt + (wr * 32 + mi * 16 + l15) * CIN +
                                             kg * 8);
            } else {
#pragma unroll
                for (int mi = 0; mi < 2; ++mi) {
                    int o = wr * 32 + mi * 16 + l15;
#pragma unroll
                    for (int j = 0; j < 8; ++j) {
                        int c = chunk * 32 + kg * 8 + j;
                        int k = c * 9 + tap;
                        A[mi][j] = (short)bf16r(weight[o * INCH + k] *
                                                style[b * INCH + k]);
                    }
                }
            }

            short8 Bv[4];
#pragma unroll
            for (int ni = 0; ni < 4; ++ni) {
                int s = sbase[ni] + kh * 34 + kw;
                int q = s >> 1;
                int g = (((s & 1) << 2) | kg) ^ (q & 7);
                Bv[ni] = *(const short8*)&xs_sm[q * 64 + g * 8];
            }
#pragma unroll
            for (int mi = 0; mi < 2; ++mi)
#pragma unroll
                for (int ni = 0; ni < 4; ++ni)
                    acc[mi][ni] = __builtin_amdgcn_mfma_f32_16x16x32_bf16(
                        A[mi], Bv[ni], acc[mi][ni], 0, 0, 0);
        }
    }

    float* op = out + ((size_t)b * OUTC) * HW;
#pragma unroll
    for (int mi = 0; mi < 2; ++mi) {
#pragma unroll
        for (int ni = 0; ni < 4; ++ni) {
            int p = wc * 64 + ni * 16 + l15;
            int h = h0 + (p >> 5), w = w0 + (p & 31);
#pragma unroll
            for (int r = 0; r < 4; ++r) {
                int o = wr * 32 + mi * 16 + kg * 4 + r;
                op[(size_t)o * HW + h * WW + w] = acc[mi][ni][r];
            }
        }
    }
}

extern "C" void kernel_launch(void* const* d_in, const int* in_sizes, int n_in,
                              void* d_out, int out_size, void* d_ws, size_t ws_size,
                              hipStream_t stream) {
    const float* x      = (const float*)d_in[0];
    const float* style  = (const float*)d_in[1];
    const float* weight = (const float*)d_in[2];
    float* out = (float*)d_out;

    const int wmod_total = BATCH * 9 * OUTC * CIN;

    if (ws_size >= XC2_BYTES + WMOD_BYTES + Z_BYTES) {
        unsigned short* xC    = (unsigned short*)d_ws;
        unsigned short* wmodp = (unsigned short*)((char*)d_ws + XC2_BYTES);
        unsigned short* zptr  = (unsigned short*)((char*)d_ws + XC2_BYTES + WMOD_BYTES);

        wmod_kernel<<<(wmod_total + 255) / 256, 256, 0, stream>>>(weight, style, wmodp);
        hipMemsetAsync(zptr, 0, Z_BYTES, stream);
        repack_kernel<<<dim3(2, HH, BATCH), 256, 0, stream>>>(x, xC);
        conv8_kernel<<<dim3(64, BATCH), 256, 0, stream>>>(xC, wmodp, zptr, out);
    } else if (ws_size >= WMOD_BYTES) {
        unsigned short* wmodp = (unsigned short*)d_ws;
        wmod_kernel<<<(wmod_total + 255) / 256, 256, 0, stream>>>(weight, style, wmodp);
        conv_kernel<true><<<dim3(256, BATCH), 512, 0, stream>>>(
            x, wmodp, nullptr, nullptr, out);
    } else {
        conv_kernel<false><<<dim3(256, BATCH), 512, 0, stream>>>(
            x, nullptr, weight, style, out);
    }
}

// Round 13
// 228.321 us; speedup vs baseline: 1.8589x; 1.8589x over previous
//
#include <hip/hip_runtime.h>
#include <hip/hip_bf16.h>

#define BATCH 8
#define CIN   128
#define HH    256
#define WW    256
#define OUTC  64
#define INCH  1152   // CIN*9
#define HW    (HH*WW)
#define WMOD_BYTES ((size_t)BATCH * 9 * OUTC * CIN * 2)

typedef __attribute__((ext_vector_type(8))) short short8;
typedef __attribute__((ext_vector_type(4))) float f32x4;

__device__ __forceinline__ unsigned short bf16r(float f) {
    unsigned u = __builtin_bit_cast(unsigned, f);
    u += 0x7fffu + ((u >> 16) & 1u);
    return (unsigned short)(u >> 16);
}

// wmod[b][tap][o][c] = bf16(weight[o][c*9+tap] * style[b][c*9+tap])
__global__ void __launch_bounds__(256) wmod_kernel(const float* __restrict__ weight,
                                                   const float* __restrict__ style,
                                                   unsigned short* __restrict__ wmod) {
    int i = blockIdx.x * 256 + threadIdx.x;
    if (i >= BATCH * 9 * OUTC * CIN) return;
    int c    = i & (CIN - 1);
    int rest = i >> 7;
    int o    = rest & (OUTC - 1);
    int bt   = rest >> 6;
    int tap  = bt % 9;
    int b    = bt / 9;
    int k    = c * 9 + tap;
    wmod[i] = bf16r(weight[o * INCH + k] * style[b * INCH + k]);
}

// conv9: single fused kernel, 1-barrier-per-chunk pipeline.
// Block 256 thr = 4 waves (wr = o-half, wc = px-half); tile 64o x (4h x 32w).
// LDS xs[2][204*32] bf16 (26 KB total): s = halo px (6x34), linear [s][c32].
// Per chunk k: loadG(k+1) [VMEM, stays in flight] -> compute(k) [ZERO VMEM:
// A preloaded, LDS+MFMA only -> staging never drained] -> loadA(k+1) [VMEM,
// drains cheaply at first A-use next chunk via counted vmcnt] -> writeG to
// other buffer [waits f via vmcnt(18), A still flying] -> ONE barrier.
// launch_bounds(256,2): VGPR cap 256 -> A[9][2]=72 + f=32 + acc=32 spill-free;
// ~180 VGPR -> 2 blocks/CU for cross-block overlap.
template <bool GW>
__global__ void __launch_bounds__(256, 2) conv9_kernel(
    const float* __restrict__ x,
    const unsigned short* __restrict__ wmod,
    const float* __restrict__ weight,
    const float* __restrict__ style,
    float* __restrict__ out)
{
    __shared__ __align__(16) unsigned short xs_sm[2][204 * 32];

    const int tid = threadIdx.x;           // 0..255
    const int bx  = blockIdx.x;            // 0..511: ht*8 + wt
    const int b   = blockIdx.y;
    const int h0  = (bx >> 3) * 4;
    const int w0  = (bx & 7) * 32;

    const int wv  = tid >> 6;
    const int wr  = wv >> 1;               // o-half
    const int wc  = wv & 1;                // px-half (w 0-15 vs 16-31)
    const int l15 = tid & 15;
    const int kg  = (tid >> 4) & 3;

    // ---- staging geometry: 240 tasks = (cg 0..3) x (r 0..5) x (qw 0..9)
    // task: 8 channels x one 16B-aligned fp32 quad; quads cover w0-4..w0+35
    // (true col = wl+u-(w0-1); OOB quads are fully OOB since 4|wl -> no
    // partial-quad index mismatch after clamp).
    const bool tv = tid < 240;
    const int tt  = tv ? tid : 0;
    const int cg  = tt / 60;
    const int rem = tt % 60;
    const int sr  = rem / 10;
    const int qw  = rem % 10;
    const int sh  = h0 - 1 + sr;
    const bool hok = tv && ((unsigned)sh < HH);
    const int wl  = w0 - 4 + qw * 4;
    const int wlc = min(max(wl, 0), WW - 4);
    const int colbase = wl - (w0 - 1);
    const float* xbase = x + ((size_t)(b * CIN + cg * 8)) * HW +
                         (hok ? sh : 0) * WW + wlc;

    f32x4  f[8];                           // staged quad (8 ch x 4 px)
    short8 A[9][2];                        // per-chunk weight fragments

    auto loadG = [&](int chunk) {
        if (hok) {
#pragma unroll
            for (int j = 0; j < 8; ++j)
                f[j] = *(const f32x4*)(xbase + (size_t)(chunk * 32 + j) * HW);
        }
    };

    auto writeG = [&](unsigned short* buf) {
        if (tv) {
#pragma unroll
            for (int u = 0; u < 4; ++u) {
                int col = colbase + u;
                if (col >= 0 && col < 34) {
                    bool wok = hok && ((unsigned)(wl + u) < WW);
                    short8 sv;
#pragma unroll
                    for (int j = 0; j < 8; ++j)
                        sv[j] = wok ? (short)bf16r(f[j][u]) : (short)0;
                    int s = sr * 34 + col;
                    *(short8*)&buf[s * 32 + cg * 8] = sv;
                }
            }
        }
    };

    auto loadA = [&](int chunk) {
        if (GW) {
            const unsigned short* wb =
                wmod + ((size_t)(b * 9) * OUTC) * CIN + chunk * 32 + kg * 8;
#pragma unroll
            for (int tap = 0; tap < 9; ++tap)
#pragma unroll
                for (int mi = 0; mi < 2; ++mi)
                    A[tap][mi] = *(const short8*)(
                        wb + ((size_t)tap * OUTC + wr * 32 + mi * 16 + l15) * CIN);
        } else {
#pragma unroll
            for (int tap = 0; tap < 9; ++tap)
#pragma unroll
                for (int mi = 0; mi < 2; ++mi) {
                    int o = wr * 32 + mi * 16 + l15;
#pragma unroll
                    for (int j = 0; j < 8; ++j) {
                        int c = chunk * 32 + kg * 8 + j;
                        int k = c * 9 + tap;
                        A[tap][mi][j] = (short)bf16r(weight[o * INCH + k] *
                                                     style[b * INCH + k]);
                    }
                }
        }
    };

    f32x4 acc[2][4];
#pragma unroll
    for (int mi = 0; mi < 2; ++mi)
#pragma unroll
        for (int ni = 0; ni < 4; ++ni) acc[mi][ni] = (f32x4){0.f, 0.f, 0.f, 0.f};

    auto compute = [&](const unsigned short* buf) {
#pragma unroll
        for (int kh = 0; kh < 3; ++kh)
#pragma unroll
            for (int kw = 0; kw < 3; ++kw) {
                const int tap = kh * 3 + kw;
                short8 Bv[4];
#pragma unroll
                for (int ni = 0; ni < 4; ++ni) {
                    int s = (ni + kh) * 34 + wc * 16 + l15 + kw;
                    Bv[ni] = *(const short8*)&buf[s * 32 + kg * 8];
                }
#pragma unroll
                for (int mi = 0; mi < 2; ++mi)
#pragma unroll
                    for (int ni = 0; ni < 4; ++ni)
                        acc[mi][ni] = __builtin_amdgcn_mfma_f32_16x16x32_bf16(
                            A[tap][mi], Bv[ni], acc[mi][ni], 0, 0, 0);
            }
    };

    // ---- prologue: chunk 0 staged; A(0) in flight behind it
    loadG(0);
    loadA(0);
    __builtin_amdgcn_sched_barrier(0);
    writeG(xs_sm[0]);                      // vmcnt waits f only (A newer)
    __syncthreads();

    // ---- chunk 0
    loadG(1);
    __builtin_amdgcn_sched_barrier(0);
    compute(xs_sm[0]);                     // zero VMEM inside
    __builtin_amdgcn_sched_barrier(0);
    loadA(1);
    writeG(xs_sm[1]);
    __syncthreads();

    // ---- chunk 1
    loadG(2);
    __builtin_amdgcn_sched_barrier(0);
    compute(xs_sm[1]);
    __builtin_amdgcn_sched_barrier(0);
    loadA(2);
    writeG(xs_sm[0]);
    __syncthreads();

    // ---- chunk 2
    loadG(3);
    __builtin_amdgcn_sched_barrier(0);
    compute(xs_sm[0]);
    __builtin_amdgcn_sched_barrier(0);
    loadA(3);
    writeG(xs_sm[1]);
    __syncthreads();

    // ---- chunk 3
    compute(xs_sm[1]);

    // ---- epilogue: D mapping col=lane&15 (pixel), row=(lane>>4)*4+r (o)
    float* op = out + ((size_t)b * OUTC) * HW + (size_t)h0 * WW + w0 + wc * 16 + l15;
#pragma unroll
    for (int mi = 0; mi < 2; ++mi)
#pragma unroll
        for (int ni = 0; ni < 4; ++ni)
#pragma unroll
            for (int rr = 0; rr < 4; ++rr) {
                int o = wr * 32 + mi * 16 + kg * 4 + rr;
                op[(size_t)o * HW + ni * WW] = acc[mi][ni][rr];
            }
}

extern "C" void kernel_launch(void* const* d_in, const int* in_sizes, int n_in,
                              void* d_out, int out_size, void* d_ws, size_t ws_size,
                              hipStream_t stream) {
    const float* x      = (const float*)d_in[0];
    const float* style  = (const float*)d_in[1];
    const float* weight = (const float*)d_in[2];
    float* out = (float*)d_out;

    const int wmod_total = BATCH * 9 * OUTC * CIN;

    if (ws_size >= WMOD_BYTES) {
        unsigned short* wmodp = (unsigned short*)d_ws;
        wmod_kernel<<<(wmod_total + 255) / 256, 256, 0, stream>>>(weight, style, wmodp);
        conv9_kernel<true><<<dim3(512, BATCH), 256, 0, stream>>>(
            x, wmodp, nullptr, nullptr, out);
    } else {
        conv9_kernel<false><<<dim3(512, BATCH), 256, 0, stream>>>(
            x, nullptr, weight, style, out);
    }
}